// Round 6
// baseline (4992.347 us; speedup 1.0000x reference)
//
#include <hip/hip_runtime.h>
#include <hip/hip_bf16.h>
#include <stdint.h>

#define T_STEPS 1024
#define NBLK    64      // recurrent blocks; each owns 8 consecutive hidden cols
#define NTHR    512     // 8 waves: wave = (mi = w>>1, nt = w&1)
#define TPB     16      // t-steps per pregemm block

typedef __attribute__((ext_vector_type(8))) short short8;
typedef __attribute__((ext_vector_type(4))) float float4v;
typedef __attribute__((ext_vector_type(2))) unsigned long long ull2;
typedef unsigned short ushort_t;
typedef unsigned long long ull;
typedef unsigned int u32;

__device__ __forceinline__ ushort_t f2bf(float f) {
    __hip_bfloat16 h = __float2bfloat16(f);  // RNE
    return __builtin_bit_cast(ushort_t, h);
}

// ---------------------------------------------------------------------------
// Setup: WiT/WhT = bf16 transpose [2048][512]; ring slot1 = h0 in [ch][row][8]
// layout; flag region (2 KB) = 0.
// ---------------------------------------------------------------------------
__global__ void lstm_setup(const float* __restrict__ Wi,
                           const float* __restrict__ Wh,
                           const float* __restrict__ h0,
                           ushort_t* __restrict__ WiT,
                           ushort_t* __restrict__ WhT,
                           ushort_t* __restrict__ ring,
                           u32* __restrict__ flag) {
    size_t i = (size_t)blockIdx.x * NTHR + threadIdx.x;
    if (i < 1048576) {
        size_t c = i >> 9, k = i & 511;
        WiT[i] = f2bf(Wi[k * 2048 + c]);
    } else if (i < 2097152) {
        size_t j = i - 1048576;
        size_t c = j >> 9, k = j & 511;
        WhT[j] = f2bf(Wh[k * 2048 + c]);
    } else if (i < 2129920) {
        size_t j = i - 2097152;          // slot1: [ch(64)][row(64)][c(8)]
        size_t ch = j >> 9, row = (j >> 3) & 63, c = j & 7;
        ring[32768 + j] = f2bf(h0[row * 512 + ch * 8 + c]);
    } else if (i < 2130432) {
        flag[i - 2129920] = 0u;
    }
}

// ---------------------------------------------------------------------------
// Bulk pre-GEMM v2 for a chunk of TC steps: zx = x @ Wi + b. (verified R4)
// Grid (TC/TPB) x 8: ng = blockIdx&7 owns recurrent blocks 8ng..8ng+7,
// tch = blockIdx>>3. BN=256: weights in registers, x_t staged once/block.
// zx layout [tc][blk(64)][row(64)][cc(8)][g(4)] fp32.
// ---------------------------------------------------------------------------
__global__ __launch_bounds__(NTHR, 2) void lstm_pregemm(
    const float* __restrict__ X,        // [1024][64][512] fp32
    const float* __restrict__ bias,     // [2048]
    const ushort_t* __restrict__ WiT,   // [2048][512] bf16
    float* __restrict__ zx,             // [TC][64][64][32]
    int t0)
{
    const int ng   = blockIdx.x & 7;
    const int tch  = blockIdx.x >> 3;
    const int tid  = threadIdx.x;
    const int lane = tid & 63;
    const int w    = tid >> 6;
    const int l15  = lane & 15;
    const int quad = lane >> 4;
    const int g    = w >> 1;            // gate 0..3
    const int half = w & 1;

    __shared__ alignas(16) char smem[65536];

    short8 wib[2][16];
    float  bv[2];
    int    blkc[2];
#pragma unroll
    for (int ct = 0; ct < 2; ct++) {
        const int c = g * 512 + ng * 64 + half * 32 + ct * 16 + l15;
        const short8* wp = (const short8*)(WiT + (size_t)c * 512);
#pragma unroll
        for (int kk = 0; kk < 16; kk++) wib[ct][kk] = wp[kk * 4 + quad];
        bv[ct]   = bias[c];
        blkc[ct] = ng * 8 + half * 4 + ct * 2 + (l15 >> 3);
    }
    const int cc = l15 & 7;

    const int xrow = tid & 63;
    const int xseg = tid >> 6;

    for (int tt = 0; tt < TPB; tt++) {
        const int tc = tch * TPB + tt;
        const int t  = t0 + tc;
        {
            const float* xb = X + (size_t)t * 32768 + xrow * 512 + xseg * 64;
#pragma unroll
            for (int jj = 0; jj < 8; jj++) {
                float4v a = *(const float4v*)(xb + jj * 8);
                float4v b = *(const float4v*)(xb + jj * 8 + 4);
                short8 p;
                p[0] = (short)f2bf(a.x); p[1] = (short)f2bf(a.y);
                p[2] = (short)f2bf(a.z); p[3] = (short)f2bf(a.w);
                p[4] = (short)f2bf(b.x); p[5] = (short)f2bf(b.y);
                p[6] = (short)f2bf(b.z); p[7] = (short)f2bf(b.w);
                *(short8*)(smem + (xseg * 8 + jj) * 1024 + xrow * 16) = p;
            }
        }
        __syncthreads();   // x staged

        float4v acc[2][4];
#pragma unroll
        for (int ct = 0; ct < 2; ct++)
#pragma unroll
            for (int rt = 0; rt < 4; rt++)
                acc[ct][rt] = (float4v){bv[ct], bv[ct], bv[ct], bv[ct]};

#pragma unroll
        for (int kk = 0; kk < 16; kk++) {
#pragma unroll
            for (int rt = 0; rt < 4; rt++) {
                short8 a = *(const short8*)(smem + (kk * 4 + quad) * 1024 +
                                            (rt * 16 + l15) * 16);
                acc[0][rt] = __builtin_amdgcn_mfma_f32_16x16x32_bf16(a, wib[0][kk], acc[0][rt], 0, 0, 0);
                acc[1][rt] = __builtin_amdgcn_mfma_f32_16x16x32_bf16(a, wib[1][kk], acc[1][rt], 0, 0, 0);
            }
        }

#pragma unroll
        for (int ct = 0; ct < 2; ct++) {
            float* zb = zx + ((size_t)(tc * 64 + blkc[ct]) * 64) * 32 + cc * 4 + g;
#pragma unroll
            for (int rt = 0; rt < 4; rt++)
#pragma unroll
                for (int r = 0; r < 4; r++)
                    zb[(size_t)(rt * 16 + quad * 4 + r) * 32] = acc[ct][rt][r];
        }
        __syncthreads();   // LDS reads done before next stage overwrites
    }
}

// ---------------------------------------------------------------------------
// Recurrent kernel v6, zx-fed, chunked [t0, t0+nsteps).
// Verified sync skeleton (R3/R4): wave-0 all-64-flag spin -> B2 -> work ->
// publish -> B5 -> flag. Change vs R4: NO LDS h-staging — each wave loads
// its MFMA A-fragments DIRECTLY from the ring in LLC via relaxed agent
// 8B atomic loads (same bytes the stage+ds_read delivered: the A-frag for
// (kk,quad,row) is the 16B at ring[((kk*4+quad)*64+row)*8]). All 32 loads
// issued up-front into registers, then 16 MFMAs. Deletes the 64KB LDS
// buffer, the global_load_lds stage, and barrier B3. LDS = ztile/hout only
// (wave-private; regroup write->read pattern identical to verified).
// 2 barriers/step (was 4).
// ---------------------------------------------------------------------------
__global__ __launch_bounds__(NTHR, 2) void lstm_persist_zx(
    const float* __restrict__ c_src,    // [64][512] (c0 or csave)
    const ushort_t* __restrict__ WhT,   // [2048][512] bf16
    const float* __restrict__ zx,       // [nsteps][64][64][32]
    ushort_t* __restrict__ ring,        // [2][64*64*8] bf16 ([ch][row][8])
    u32* __restrict__ flag,             // [64] spread at stride 8 words
    float* __restrict__ out,            // ys | cT | hT
    int t0, int nsteps,
    float* __restrict__ csave)          // [64][512]
{
    const int blk  = blockIdx.x;
    const int tid  = threadIdx.x;
    const int lane = tid & 63;
    const int w    = tid >> 6;
    const int l15  = lane & 15;
    const int quad = lane >> 4;
    const int nt   = w & 1;
    const int mi   = w >> 1;

    __shared__ alignas(16) char smem[9728];   // ztile (8x1088) + hout (8x128)

    const int col = (l15 >> 2) * 512 + blk * 8 + nt * 4 + (l15 & 3);
    short8 whb[16];
    {
        const short8* hp = (const short8*)(WhT + (size_t)col * 512);
#pragma unroll
        for (int kk = 0; kk < 16; kk++) whb[kk] = hp[kk * 4 + quad];
    }

    const int crow = mi * 16 + quad * 4 + (l15 >> 2);
    const int ccol = nt * 4 + (l15 & 3);          // local hidden col 0..7
    float c_reg = c_src[crow * 512 + blk * 8 + ccol];

    float*    ztile_w = (float*)(smem + w * 1088);
    ushort_t* hout_w  = (ushort_t*)(smem + 8704 + w * 128);

    const float* zbase = zx + (size_t)blk * 2048 + (size_t)crow * 32 + ccol * 4;
    // A-frag source offset (ushorts): chunk (kk*4+quad), row (mi*16+l15)
    const size_t aoff = (size_t)quad * 512 + (size_t)(mi * 16 + l15) * 8;

    for (int tc = 0; tc < nsteps; tc++) {
        const int t = t0 + tc;

        // ---- prefetch zx (in flight during spin) ----
        float4v zx4 = *(const float4v*)(zbase + (size_t)tc * 131072);

        // ---- wait for all h_{t-1} flags (wave 0, verified predicate) ----
        if (t > 0 && w == 0) {
            const unsigned tgt = (unsigned)t;
            for (;;) {
                unsigned v = __hip_atomic_load(&flag[lane * 8], __ATOMIC_RELAXED,
                                               __HIP_MEMORY_SCOPE_AGENT);
                if (__ballot(v >= tgt) == ~0ull) break;
                __builtin_amdgcn_s_sleep(1);
            }
        }
        __syncthreads();   // B2: h_{t-1} published everywhere

        // ---- load A-fragments directly from ring (LLC) into registers ----
        const ushort_t* rslot = ring + (size_t)((t + 1) & 1) * 32768;
        short8 afrag[16];
#pragma unroll
        for (int kk = 0; kk < 16; kk++) {
            const ull* p = (const ull*)(rslot + (size_t)kk * 2048 + aoff);
            ull lo = __hip_atomic_load(p,     __ATOMIC_RELAXED, __HIP_MEMORY_SCOPE_AGENT);
            ull hi = __hip_atomic_load(p + 1, __ATOMIC_RELAXED, __HIP_MEMORY_SCOPE_AGENT);
            ull2 v; v.x = lo; v.y = hi;
            afrag[kk] = __builtin_bit_cast(short8, v);
        }

        // ---- h_{t-1} @ Wh ----
        float4v acc = {0.f, 0.f, 0.f, 0.f};
#pragma unroll
        for (int kk = 0; kk < 16; kk++)
            acc = __builtin_amdgcn_mfma_f32_16x16x32_bf16(afrag[kk], whb[kk], acc, 0, 0, 0);

        // ---- wave-private gate regroup (verified pattern) + zx add ----
#pragma unroll
        for (int r = 0; r < 4; r++)
            ztile_w[(quad * 4 + r) * 17 + l15] = acc[r];
        float zi = ztile_w[(quad * 4 + (l15 >> 2)) * 17 + 0  + (l15 & 3)] + zx4.x;
        float zf = ztile_w[(quad * 4 + (l15 >> 2)) * 17 + 4  + (l15 & 3)] + zx4.y;
        float zg = ztile_w[(quad * 4 + (l15 >> 2)) * 17 + 8  + (l15 & 3)] + zx4.z;
        float zo = ztile_w[(quad * 4 + (l15 >> 2)) * 17 + 12 + (l15 & 3)] + zx4.w;
        float si = 1.f / (1.f + __expf(-zi));
        float sf = 1.f / (1.f + __expf(-zf));
        float tg = tanhf(zg);
        float so = 1.f / (1.f + __expf(-zo));
        float nc = sf * c_reg + si * tg;
        float nh = so * tanhf(nc);
        c_reg = nc;
        hout_w[(quad * 4 + (l15 >> 2)) * 4 + (l15 & 3)] = f2bf(nh);

        // ---- publish h_t: wave-local 8B chunks as relaxed agent stores ----
        if (lane < 16) {
            ull v = *(const ull*)(hout_w + lane * 4);
            ull* dst = (ull*)(ring + (size_t)(t & 1) * 32768 +
                              blk * 512 + (mi * 16 + lane) * 8 + nt * 4);
            __hip_atomic_store(dst, v, __ATOMIC_RELAXED, __HIP_MEMORY_SCOPE_AGENT);
        }
        __syncthreads();   // B5: all ring stores + ring loads drained
        if (tid == 0)
            __hip_atomic_store(&flag[blk * 8], (unsigned)(t + 1),
                               __ATOMIC_RELAXED, __HIP_MEMORY_SCOPE_AGENT);

        // ---- ys / final-state stores off the critical path ----
        out[(size_t)t * 32768 + crow * 512 + blk * 8 + ccol] = nh;
        if (t == T_STEPS - 1) {
            out[33554432u + crow * 512 + blk * 8 + ccol] = nc;           // cT
            out[33554432u + 32768u + crow * 512 + blk * 8 + ccol] = nh;  // hT
        }
    }

    csave[crow * 512 + blk * 8 + ccol] = c_reg;
}

// ---------------------------------------------------------------------------
// Fallback (verified) for tiny workspaces: full per-step x-stage + x@Wi.
// ---------------------------------------------------------------------------
__global__ __launch_bounds__(NTHR, 2) void lstm_persist(
    const float* __restrict__ X,
    const float* __restrict__ c0,
    const float* __restrict__ bias,
    const ushort_t* __restrict__ WiT,
    const ushort_t* __restrict__ WhT,
    ushort_t* __restrict__ ring,
    u32* __restrict__ flag,
    float* __restrict__ out)
{
    const int blk  = blockIdx.x;
    const int tid  = threadIdx.x;
    const int lane = tid & 63;
    const int w    = tid >> 6;
    const int l15  = lane & 15;
    const int quad = lane >> 4;
    const int nt   = w & 1;
    const int mi   = w >> 1;

    __shared__ alignas(16) char smem[65536];

    const int col = (l15 >> 2) * 512 + blk * 8 + nt * 4 + (l15 & 3);
    short8 wib[16], whb[16];
    {
        const short8* wp = (const short8*)(WiT + (size_t)col * 512);
        const short8* hp = (const short8*)(WhT + (size_t)col * 512);
#pragma unroll
        for (int kk = 0; kk < 16; kk++) {
            wib[kk] = wp[kk * 4 + quad];
            whb[kk] = hp[kk * 4 + quad];
        }
    }
    const float bval = bias[col];

    const int crow = mi * 16 + quad * 4 + (l15 >> 2);
    const int ccol = nt * 4 + (l15 & 3);
    float c_reg = c0[crow * 512 + blk * 8 + ccol];

    const int xrow = tid & 63;
    const int xseg = tid >> 6;

    float*    ztile_w = (float*)(smem + w * 1088);
    ushort_t* hout_w  = (ushort_t*)(smem + 8704 + w * 128);

    for (int t = 0; t < T_STEPS; t++) {
        {
            const float* xb = X + (size_t)t * 32768 + xrow * 512 + xseg * 64;
#pragma unroll
            for (int jj = 0; jj < 8; jj++) {
                float4v a = *(const float4v*)(xb + jj * 8);
                float4v b = *(const float4v*)(xb + jj * 8 + 4);
                short8 p;
                p[0] = (short)f2bf(a.x); p[1] = (short)f2bf(a.y);
                p[2] = (short)f2bf(a.z); p[3] = (short)f2bf(a.w);
                p[4] = (short)f2bf(b.x); p[5] = (short)f2bf(b.y);
                p[6] = (short)f2bf(b.z); p[7] = (short)f2bf(b.w);
                *(short8*)(smem + (xseg * 8 + jj) * 1024 + xrow * 16) = p;
            }
        }
        __syncthreads();

        float4v acc = {bval, bval, bval, bval};
#pragma unroll
        for (int kk = 0; kk < 16; kk++) {
            short8 a = *(const short8*)(smem + (kk * 4 + quad) * 1024 +
                                        (mi * 16 + l15) * 16);
            acc = __builtin_amdgcn_mfma_f32_16x16x32_bf16(a, wib[kk], acc, 0, 0, 0);
        }

        if (t > 0 && w == 0) {
            const unsigned tgt = (unsigned)t;
            for (;;) {
                unsigned v = __hip_atomic_load(&flag[lane * 8], __ATOMIC_RELAXED,
                                               __HIP_MEMORY_SCOPE_AGENT);
                if (__ballot(v >= tgt) == ~0ull) break;
                __builtin_amdgcn_s_sleep(1);
            }
        }
        __syncthreads();

        {
            const ushort_t* rslot = ring + (size_t)((t + 1) & 1) * 32768;
#pragma unroll
            for (int j = 0; j < 8; j++) {
                int f = w * 8 + j;
                const u32 __attribute__((address_space(1)))* gp =
                    (const u32 __attribute__((address_space(1)))*)(rslot + f * 512 + lane * 8);
                u32 __attribute__((address_space(3)))* lp =
                    (u32 __attribute__((address_space(3)))*)(smem + f * 1024);
                __builtin_amdgcn_global_load_lds(gp, lp, 16, 0, 17);
            }
        }
        __syncthreads();

#pragma unroll
        for (int kk = 0; kk < 16; kk++) {
            short8 a = *(const short8*)(smem + (kk * 4 + quad) * 1024 +
                                        (mi * 16 + l15) * 16);
            acc = __builtin_amdgcn_mfma_f32_16x16x32_bf16(a, whb[kk], acc, 0, 0, 0);
        }
        __syncthreads();

#pragma unroll
        for (int r = 0; r < 4; r++)
            ztile_w[(quad * 4 + r) * 17 + l15] = acc[r];
        float zi = ztile_w[(quad * 4 + (l15 >> 2)) * 17 + 0  + (l15 & 3)];
        float zf = ztile_w[(quad * 4 + (l15 >> 2)) * 17 + 4  + (l15 & 3)];
        float zg = ztile_w[(quad * 4 + (l15 >> 2)) * 17 + 8  + (l15 & 3)];
        float zo = ztile_w[(quad * 4 + (l15 >> 2)) * 17 + 12 + (l15 & 3)];
        float si = 1.f / (1.f + __expf(-zi));
        float sf = 1.f / (1.f + __expf(-zf));
        float tg = tanhf(zg);
        float so = 1.f / (1.f + __expf(-zo));
        float nc = sf * c_reg + si * tg;
        float nh = so * tanhf(nc);
        c_reg = nc;
        hout_w[(quad * 4 + (l15 >> 2)) * 4 + (l15 & 3)] = f2bf(nh);

        if (lane < 16) {
            ull v = *(const ull*)(hout_w + lane * 4);
            ull* dst = (ull*)(ring + (size_t)(t & 1) * 32768 +
                              blk * 512 + (mi * 16 + lane) * 8 + nt * 4);
            __hip_atomic_store(dst, v, __ATOMIC_RELAXED, __HIP_MEMORY_SCOPE_AGENT);
        }
        __syncthreads();
        if (tid == 0)
            __hip_atomic_store(&flag[blk * 8], (unsigned)(t + 1),
                               __ATOMIC_RELAXED, __HIP_MEMORY_SCOPE_AGENT);

        out[(size_t)t * 32768 + crow * 512 + blk * 8 + ccol] = nh;
        if (t == T_STEPS - 1) {
            out[33554432u + crow * 512 + blk * 8 + ccol] = nc;
            out[33554432u + 32768u + crow * 512 + blk * 8 + ccol] = nh;
        }
    }
}

// ---------------------------------------------------------------------------
extern "C" void kernel_launch(void* const* d_in, const int* in_sizes, int n_in,
                              void* d_out, int out_size, void* d_ws, size_t ws_size,
                              hipStream_t stream) {
    const float* X    = (const float*)d_in[0];   // [1024][64][512]
    const float* c0   = (const float*)d_in[1];   // [64][512]
    const float* h0   = (const float*)d_in[2];   // [64][512]
    const float* Wi   = (const float*)d_in[3];   // [512][2048]
    const float* Wh   = (const float*)d_in[4];   // [512][2048]
    const float* bias = (const float*)d_in[5];   // [2048]

    char* ws = (char*)d_ws;
    ushort_t* WiT   = (ushort_t*)ws;                   //  2,097,152 B
    ushort_t* WhT   = (ushort_t*)(ws + 2097152);       //  2,097,152 B
    ushort_t* ring  = (ushort_t*)(ws + 4194304);       //    131,072 B
    u32*      flag  = (u32*)(ws + 4325376);            //      2,048 B
    float*    csave = (float*)(ws + 4327424);          //    131,072 B
    // zx chunk buffer at +4,458,496: TC * 512 KB

    lstm_setup<<<4161, NTHR, 0, stream>>>(Wi, Wh, h0, WiT, WhT, ring, flag);

    const size_t ZXOFF = 4458496ull;
    int TC = 0;
    const int cands[6] = {1024, 512, 256, 128, 64, 32};
    for (int i = 0; i < 6; i++) {
        if (ZXOFF + (size_t)cands[i] * 524288ull <= ws_size) { TC = cands[i]; break; }
    }

    if (TC) {
        float* zx = (float*)(ws + ZXOFF);
        const int nch = T_STEPS / TC;
        for (int c = 0; c < nch; c++) {
            const int t0 = c * TC;
            lstm_pregemm<<<(TC / TPB) * 8, NTHR, 0, stream>>>(X, bias, WiT, zx, t0);
            lstm_persist_zx<<<NBLK, NTHR, 0, stream>>>(
                c ? (const float*)csave : c0, WhT, zx, ring, flag,
                (float*)d_out, t0, TC, csave);
        }
    } else {
        lstm_persist<<<NBLK, NTHR, 0, stream>>>(X, c0, bias, WiT, WhT, ring, flag,
                                                (float*)d_out);
    }
}

// Round 7
// 3263.000 us; speedup vs baseline: 1.5300x; 1.5300x over previous
//
#include <hip/hip_runtime.h>
#include <hip/hip_bf16.h>
#include <stdint.h>

#define T_STEPS 1024
#define NBLK    64      // recurrent blocks; each owns 8 consecutive hidden cols
#define NTHR    512     // 8 waves: wave = (mi = w>>1, nt = w&1)
#define TPB     16      // t-steps per pregemm block

typedef __attribute__((ext_vector_type(8))) short short8;
typedef __attribute__((ext_vector_type(4))) float float4v;
typedef unsigned short ushort_t;
typedef unsigned long long ull;
typedef unsigned int u32;

__device__ __forceinline__ ushort_t f2bf(float f) {
    __hip_bfloat16 h = __float2bfloat16(f);  // RNE
    return __builtin_bit_cast(ushort_t, h);
}

// ---------------------------------------------------------------------------
// Setup: WiT/WhT = bf16 transpose [2048][512]; ring slot1 = h0 in [ch][row][8]
// layout; flag region (2 KB) = 0.
// ---------------------------------------------------------------------------
__global__ void lstm_setup(const float* __restrict__ Wi,
                           const float* __restrict__ Wh,
                           const float* __restrict__ h0,
                           ushort_t* __restrict__ WiT,
                           ushort_t* __restrict__ WhT,
                           ushort_t* __restrict__ ring,
                           u32* __restrict__ flag) {
    size_t i = (size_t)blockIdx.x * NTHR + threadIdx.x;
    if (i < 1048576) {
        size_t c = i >> 9, k = i & 511;
        WiT[i] = f2bf(Wi[k * 2048 + c]);
    } else if (i < 2097152) {
        size_t j = i - 1048576;
        size_t c = j >> 9, k = j & 511;
        WhT[j] = f2bf(Wh[k * 2048 + c]);
    } else if (i < 2129920) {
        size_t j = i - 2097152;          // slot1: [ch(64)][row(64)][c(8)]
        size_t ch = j >> 9, row = (j >> 3) & 63, c = j & 7;
        ring[32768 + j] = f2bf(h0[row * 512 + ch * 8 + c]);
    } else if (i < 2130432) {
        flag[i - 2129920] = 0u;
    }
}

// ---------------------------------------------------------------------------
// Bulk pre-GEMM v2 for a chunk of TC steps: zx = x @ Wi + b. (verified R4)
// Grid (TC/TPB) x 8: ng = blockIdx&7 owns recurrent blocks 8ng..8ng+7,
// tch = blockIdx>>3. BN=256: weights in registers, x_t staged once/block.
// zx layout [tc][blk(64)][row(64)][cc(8)][g(4)] fp32.
// ---------------------------------------------------------------------------
__global__ __launch_bounds__(NTHR, 2) void lstm_pregemm(
    const float* __restrict__ X,        // [1024][64][512] fp32
    const float* __restrict__ bias,     // [2048]
    const ushort_t* __restrict__ WiT,   // [2048][512] bf16
    float* __restrict__ zx,             // [TC][64][64][32]
    int t0)
{
    const int ng   = blockIdx.x & 7;
    const int tch  = blockIdx.x >> 3;
    const int tid  = threadIdx.x;
    const int lane = tid & 63;
    const int w    = tid >> 6;
    const int l15  = lane & 15;
    const int quad = lane >> 4;
    const int g    = w >> 1;            // gate 0..3
    const int half = w & 1;

    __shared__ alignas(16) char smem[65536];

    short8 wib[2][16];
    float  bv[2];
    int    blkc[2];
#pragma unroll
    for (int ct = 0; ct < 2; ct++) {
        const int c = g * 512 + ng * 64 + half * 32 + ct * 16 + l15;
        const short8* wp = (const short8*)(WiT + (size_t)c * 512);
#pragma unroll
        for (int kk = 0; kk < 16; kk++) wib[ct][kk] = wp[kk * 4 + quad];
        bv[ct]   = bias[c];
        blkc[ct] = ng * 8 + half * 4 + ct * 2 + (l15 >> 3);
    }
    const int cc = l15 & 7;

    const int xrow = tid & 63;
    const int xseg = tid >> 6;

    for (int tt = 0; tt < TPB; tt++) {
        const int tc = tch * TPB + tt;
        const int t  = t0 + tc;
        {
            const float* xb = X + (size_t)t * 32768 + xrow * 512 + xseg * 64;
#pragma unroll
            for (int jj = 0; jj < 8; jj++) {
                float4v a = *(const float4v*)(xb + jj * 8);
                float4v b = *(const float4v*)(xb + jj * 8 + 4);
                short8 p;
                p[0] = (short)f2bf(a.x); p[1] = (short)f2bf(a.y);
                p[2] = (short)f2bf(a.z); p[3] = (short)f2bf(a.w);
                p[4] = (short)f2bf(b.x); p[5] = (short)f2bf(b.y);
                p[6] = (short)f2bf(b.z); p[7] = (short)f2bf(b.w);
                *(short8*)(smem + (xseg * 8 + jj) * 1024 + xrow * 16) = p;
            }
        }
        __syncthreads();   // x staged

        float4v acc[2][4];
#pragma unroll
        for (int ct = 0; ct < 2; ct++)
#pragma unroll
            for (int rt = 0; rt < 4; rt++)
                acc[ct][rt] = (float4v){bv[ct], bv[ct], bv[ct], bv[ct]};

#pragma unroll
        for (int kk = 0; kk < 16; kk++) {
#pragma unroll
            for (int rt = 0; rt < 4; rt++) {
                short8 a = *(const short8*)(smem + (kk * 4 + quad) * 1024 +
                                            (rt * 16 + l15) * 16);
                acc[0][rt] = __builtin_amdgcn_mfma_f32_16x16x32_bf16(a, wib[0][kk], acc[0][rt], 0, 0, 0);
                acc[1][rt] = __builtin_amdgcn_mfma_f32_16x16x32_bf16(a, wib[1][kk], acc[1][rt], 0, 0, 0);
            }
        }

#pragma unroll
        for (int ct = 0; ct < 2; ct++) {
            float* zb = zx + ((size_t)(tc * 64 + blkc[ct]) * 64) * 32 + cc * 4 + g;
#pragma unroll
            for (int rt = 0; rt < 4; rt++)
#pragma unroll
                for (int r = 0; r < 4; r++)
                    zb[(size_t)(rt * 16 + quad * 4 + r) * 32] = acc[ct][rt][r];
        }
        __syncthreads();   // LDS reads done before next stage overwrites
    }
}

// ---------------------------------------------------------------------------
// Recurrent kernel v7, zx-fed, chunked [t0, t0+nsteps).
// = R4 verified structure with ONE change: ztile/hout moved to a DISJOINT
// LDS region (beyond the 64 KB h-buffer), so the overlay-protection barrier
// (R4's B4) is removed. Disjoint wave-private regroup proven correct in R6.
// Spin: wave 0 on all 64 flags (the only spin variant that has ever passed).
// 3 barriers/step: B2 (h published), B3 (h staged), B5 (publish drained).
// ---------------------------------------------------------------------------
__global__ __launch_bounds__(NTHR, 2) void lstm_persist_zx(
    const float* __restrict__ c_src,    // [64][512] (c0 or csave)
    const ushort_t* __restrict__ WhT,   // [2048][512] bf16
    const float* __restrict__ zx,       // [nsteps][64][64][32]
    ushort_t* __restrict__ ring,        // [2][64*64*8] bf16 ([ch][row][8])
    u32* __restrict__ flag,             // [64] spread at stride 8 words
    float* __restrict__ out,            // ys | cT | hT
    int t0, int nsteps,
    float* __restrict__ csave)          // [64][512]
{
    const int blk  = blockIdx.x;
    const int tid  = threadIdx.x;
    const int lane = tid & 63;
    const int w    = tid >> 6;
    const int l15  = lane & 15;
    const int quad = lane >> 4;
    const int nt   = w & 1;
    const int mi   = w >> 1;

    // 64 KB h-buffer + disjoint 9728 B ztile/hout region (2 blocks/CU)
    __shared__ alignas(16) char smem[75264];

    const int col = (l15 >> 2) * 512 + blk * 8 + nt * 4 + (l15 & 3);
    short8 whb[16];
    {
        const short8* hp = (const short8*)(WhT + (size_t)col * 512);
#pragma unroll
        for (int kk = 0; kk < 16; kk++) whb[kk] = hp[kk * 4 + quad];
    }

    const int crow = mi * 16 + quad * 4 + (l15 >> 2);
    const int ccol = nt * 4 + (l15 & 3);          // local hidden col 0..7
    float c_reg = c_src[crow * 512 + blk * 8 + ccol];

    float*    ztile_w = (float*)(smem + 65536 + w * 1088);
    ushort_t* hout_w  = (ushort_t*)(smem + 65536 + 8704 + w * 128);

    const float* zbase = zx + (size_t)blk * 2048 + (size_t)crow * 32 + ccol * 4;

    for (int tc = 0; tc < nsteps; tc++) {
        const int t = t0 + tc;

        // ---- prefetch zx (in flight during spin + h stage) ----
        float4v zx4 = *(const float4v*)(zbase + (size_t)tc * 131072);

        // ---- wait for all h_{t-1} flags (wave 0, verified predicate) ----
        if (t > 0 && w == 0) {
            const unsigned tgt = (unsigned)t;
            for (;;) {
                unsigned v = __hip_atomic_load(&flag[lane * 8], __ATOMIC_RELAXED,
                                               __HIP_MEMORY_SCOPE_AGENT);
                if (__ballot(v >= tgt) == ~0ull) break;
                __builtin_amdgcn_s_sleep(1);
            }
        }
        __syncthreads();   // B2: h_{t-1} published everywhere

        // ---- stage h_{t-1}: ring -> LDS via global_load_lds (sc0|sc1=17) ----
        {
            const ushort_t* rslot = ring + (size_t)((t + 1) & 1) * 32768;
#pragma unroll
            for (int j = 0; j < 8; j++) {
                int f = w * 8 + j;
                const u32 __attribute__((address_space(1)))* gp =
                    (const u32 __attribute__((address_space(1)))*)(rslot + f * 512 + lane * 8);
                u32 __attribute__((address_space(3)))* lp =
                    (u32 __attribute__((address_space(3)))*)(smem + f * 1024);
                __builtin_amdgcn_global_load_lds(gp, lp, 16, 0, 17);
            }
        }
        __syncthreads();   // B3: h staged (vmcnt drained by barrier)

        // ---- h_{t-1} @ Wh ----
        float4v acc = {0.f, 0.f, 0.f, 0.f};
#pragma unroll
        for (int kk = 0; kk < 16; kk++) {
            short8 a = *(const short8*)(smem + (kk * 4 + quad) * 1024 +
                                        (mi * 16 + l15) * 16);
            acc = __builtin_amdgcn_mfma_f32_16x16x32_bf16(a, whb[kk], acc, 0, 0, 0);
        }

        // ---- wave-private gate regroup (disjoint LDS, no barrier; R6) ----
#pragma unroll
        for (int r = 0; r < 4; r++)
            ztile_w[(quad * 4 + r) * 17 + l15] = acc[r];
        float zi = ztile_w[(quad * 4 + (l15 >> 2)) * 17 + 0  + (l15 & 3)] + zx4.x;
        float zf = ztile_w[(quad * 4 + (l15 >> 2)) * 17 + 4  + (l15 & 3)] + zx4.y;
        float zg = ztile_w[(quad * 4 + (l15 >> 2)) * 17 + 8  + (l15 & 3)] + zx4.z;
        float zo = ztile_w[(quad * 4 + (l15 >> 2)) * 17 + 12 + (l15 & 3)] + zx4.w;
        float si = 1.f / (1.f + __expf(-zi));
        float sf = 1.f / (1.f + __expf(-zf));
        float tg = tanhf(zg);
        float so = 1.f / (1.f + __expf(-zo));
        float nc = sf * c_reg + si * tg;
        float nh = so * tanhf(nc);
        c_reg = nc;
        hout_w[(quad * 4 + (l15 >> 2)) * 4 + (l15 & 3)] = f2bf(nh);

        // ---- publish h_t: wave-local 8B chunks as relaxed agent stores ----
        if (lane < 16) {
            ull v = *(const ull*)(hout_w + lane * 4);
            ull* dst = (ull*)(ring + (size_t)(t & 1) * 32768 +
                              blk * 512 + (mi * 16 + lane) * 8 + nt * 4);
            __hip_atomic_store(dst, v, __ATOMIC_RELAXED, __HIP_MEMORY_SCOPE_AGENT);
        }
        __syncthreads();   // B5: all ring stores drained (vmcnt(0) at barrier)
        if (tid == 0)
            __hip_atomic_store(&flag[blk * 8], (unsigned)(t + 1),
                               __ATOMIC_RELAXED, __HIP_MEMORY_SCOPE_AGENT);

        // ---- ys / final-state stores off the critical path ----
        out[(size_t)t * 32768 + crow * 512 + blk * 8 + ccol] = nh;
        if (t == T_STEPS - 1) {
            out[33554432u + crow * 512 + blk * 8 + ccol] = nc;           // cT
            out[33554432u + 32768u + crow * 512 + blk * 8 + ccol] = nh;  // hT
        }
    }

    csave[crow * 512 + blk * 8 + ccol] = c_reg;
}

// ---------------------------------------------------------------------------
// Fallback (verified) for tiny workspaces: full per-step x-stage + x@Wi.
// ---------------------------------------------------------------------------
__global__ __launch_bounds__(NTHR, 2) void lstm_persist(
    const float* __restrict__ X,
    const float* __restrict__ c0,
    const float* __restrict__ bias,
    const ushort_t* __restrict__ WiT,
    const ushort_t* __restrict__ WhT,
    ushort_t* __restrict__ ring,
    u32* __restrict__ flag,
    float* __restrict__ out)
{
    const int blk  = blockIdx.x;
    const int tid  = threadIdx.x;
    const int lane = tid & 63;
    const int w    = tid >> 6;
    const int l15  = lane & 15;
    const int quad = lane >> 4;
    const int nt   = w & 1;
    const int mi   = w >> 1;

    __shared__ alignas(16) char smem[65536];

    const int col = (l15 >> 2) * 512 + blk * 8 + nt * 4 + (l15 & 3);
    short8 wib[16], whb[16];
    {
        const short8* wp = (const short8*)(WiT + (size_t)col * 512);
        const short8* hp = (const short8*)(WhT + (size_t)col * 512);
#pragma unroll
        for (int kk = 0; kk < 16; kk++) {
            wib[kk] = wp[kk * 4 + quad];
            whb[kk] = hp[kk * 4 + quad];
        }
    }
    const float bval = bias[col];

    const int crow = mi * 16 + quad * 4 + (l15 >> 2);
    const int ccol = nt * 4 + (l15 & 3);
    float c_reg = c0[crow * 512 + blk * 8 + ccol];

    const int xrow = tid & 63;
    const int xseg = tid >> 6;

    float*    ztile_w = (float*)(smem + w * 1088);
    ushort_t* hout_w  = (ushort_t*)(smem + 8704 + w * 128);

    for (int t = 0; t < T_STEPS; t++) {
        {
            const float* xb = X + (size_t)t * 32768 + xrow * 512 + xseg * 64;
#pragma unroll
            for (int jj = 0; jj < 8; jj++) {
                float4v a = *(const float4v*)(xb + jj * 8);
                float4v b = *(const float4v*)(xb + jj * 8 + 4);
                short8 p;
                p[0] = (short)f2bf(a.x); p[1] = (short)f2bf(a.y);
                p[2] = (short)f2bf(a.z); p[3] = (short)f2bf(a.w);
                p[4] = (short)f2bf(b.x); p[5] = (short)f2bf(b.y);
                p[6] = (short)f2bf(b.z); p[7] = (short)f2bf(b.w);
                *(short8*)(smem + (xseg * 8 + jj) * 1024 + xrow * 16) = p;
            }
        }
        __syncthreads();

        float4v acc = {bval, bval, bval, bval};
#pragma unroll
        for (int kk = 0; kk < 16; kk++) {
            short8 a = *(const short8*)(smem + (kk * 4 + quad) * 1024 +
                                        (mi * 16 + l15) * 16);
            acc = __builtin_amdgcn_mfma_f32_16x16x32_bf16(a, wib[kk], acc, 0, 0, 0);
        }

        if (t > 0 && w == 0) {
            const unsigned tgt = (unsigned)t;
            for (;;) {
                unsigned v = __hip_atomic_load(&flag[lane * 8], __ATOMIC_RELAXED,
                                               __HIP_MEMORY_SCOPE_AGENT);
                if (__ballot(v >= tgt) == ~0ull) break;
                __builtin_amdgcn_s_sleep(1);
            }
        }
        __syncthreads();

        {
            const ushort_t* rslot = ring + (size_t)((t + 1) & 1) * 32768;
#pragma unroll
            for (int j = 0; j < 8; j++) {
                int f = w * 8 + j;
                const u32 __attribute__((address_space(1)))* gp =
                    (const u32 __attribute__((address_space(1)))*)(rslot + f * 512 + lane * 8);
                u32 __attribute__((address_space(3)))* lp =
                    (u32 __attribute__((address_space(3)))*)(smem + f * 1024);
                __builtin_amdgcn_global_load_lds(gp, lp, 16, 0, 17);
            }
        }
        __syncthreads();

#pragma unroll
        for (int kk = 0; kk < 16; kk++) {
            short8 a = *(const short8*)(smem + (kk * 4 + quad) * 1024 +
                                        (mi * 16 + l15) * 16);
            acc = __builtin_amdgcn_mfma_f32_16x16x32_bf16(a, whb[kk], acc, 0, 0, 0);
        }
        __syncthreads();

#pragma unroll
        for (int r = 0; r < 4; r++)
            ztile_w[(quad * 4 + r) * 17 + l15] = acc[r];
        float zi = ztile_w[(quad * 4 + (l15 >> 2)) * 17 + 0  + (l15 & 3)];
        float zf = ztile_w[(quad * 4 + (l15 >> 2)) * 17 + 4  + (l15 & 3)];
        float zg = ztile_w[(quad * 4 + (l15 >> 2)) * 17 + 8  + (l15 & 3)];
        float zo = ztile_w[(quad * 4 + (l15 >> 2)) * 17 + 12 + (l15 & 3)];
        float si = 1.f / (1.f + __expf(-zi));
        float sf = 1.f / (1.f + __expf(-zf));
        float tg = tanhf(zg);
        float so = 1.f / (1.f + __expf(-zo));
        float nc = sf * c_reg + si * tg;
        float nh = so * tanhf(nc);
        c_reg = nc;
        hout_w[(quad * 4 + (l15 >> 2)) * 4 + (l15 & 3)] = f2bf(nh);

        if (lane < 16) {
            ull v = *(const ull*)(hout_w + lane * 4);
            ull* dst = (ull*)(ring + (size_t)(t & 1) * 32768 +
                              blk * 512 + (mi * 16 + lane) * 8 + nt * 4);
            __hip_atomic_store(dst, v, __ATOMIC_RELAXED, __HIP_MEMORY_SCOPE_AGENT);
        }
        __syncthreads();
        if (tid == 0)
            __hip_atomic_store(&flag[blk * 8], (unsigned)(t + 1),
                               __ATOMIC_RELAXED, __HIP_MEMORY_SCOPE_AGENT);

        out[(size_t)t * 32768 + crow * 512 + blk * 8 + ccol] = nh;
        if (t == T_STEPS - 1) {
            out[33554432u + crow * 512 + blk * 8 + ccol] = nc;
            out[33554432u + 32768u + crow * 512 + blk * 8 + ccol] = nh;
        }
    }
}

// ---------------------------------------------------------------------------
extern "C" void kernel_launch(void* const* d_in, const int* in_sizes, int n_in,
                              void* d_out, int out_size, void* d_ws, size_t ws_size,
                              hipStream_t stream) {
    const float* X    = (const float*)d_in[0];   // [1024][64][512]
    const float* c0   = (const float*)d_in[1];   // [64][512]
    const float* h0   = (const float*)d_in[2];   // [64][512]
    const float* Wi   = (const float*)d_in[3];   // [512][2048]
    const float* Wh   = (const float*)d_in[4];   // [512][2048]
    const float* bias = (const float*)d_in[5];   // [2048]

    char* ws = (char*)d_ws;
    ushort_t* WiT   = (ushort_t*)ws;                   //  2,097,152 B
    ushort_t* WhT   = (ushort_t*)(ws + 2097152);       //  2,097,152 B
    ushort_t* ring  = (ushort_t*)(ws + 4194304);       //    131,072 B
    u32*      flag  = (u32*)(ws + 4325376);            //      2,048 B
    float*    csave = (float*)(ws + 4327424);          //    131,072 B
    // zx chunk buffer at +4,458,496: TC * 512 KB

    lstm_setup<<<4161, NTHR, 0, stream>>>(Wi, Wh, h0, WiT, WhT, ring, flag);

    const size_t ZXOFF = 4458496ull;
    int TC = 0;
    const int cands[6] = {1024, 512, 256, 128, 64, 32};
    for (int i = 0; i < 6; i++) {
        if (ZXOFF + (size_t)cands[i] * 524288ull <= ws_size) { TC = cands[i]; break; }
    }

    if (TC) {
        float* zx = (float*)(ws + ZXOFF);
        const int nch = T_STEPS / TC;
        for (int c = 0; c < nch; c++) {
            const int t0 = c * TC;
            lstm_pregemm<<<(TC / TPB) * 8, NTHR, 0, stream>>>(X, bias, WiT, zx, t0);
            lstm_persist_zx<<<NBLK, NTHR, 0, stream>>>(
                c ? (const float*)csave : c0, WhT, zx, ring, flag,
                (float*)d_out, t0, TC, csave);
        }
    } else {
        lstm_persist<<<NBLK, NTHR, 0, stream>>>(X, c0, bias, WiT, WhT, ring, flag,
                                                (float*)d_out);
    }
}